// Round 3
// baseline (1172.382 us; speedup 1.0000x reference)
//
#include <hip/hip_runtime.h>
#include <hip/hip_cooperative_groups.h>
#include <cstdint>

namespace cg = cooperative_groups;

static constexpr int C     = 5;
static constexpr int MAXP  = 10;
static constexpr int MAXV  = 160000;
static constexpr int BLK   = 256;
static constexpr int RBITS = 9;
static constexpr int RBUCK = 1 << RBITS;   // 512 buckets
static constexpr int EPT   = 8;            // elements per thread
static constexpr int ELEMS = BLK * EPT;    // 2048 elements per block

// Output layout (float32, concatenated in reference return order)
static constexpr int VOX_OFF = 0;                           // 160000*10*5
static constexpr int CO_OFF  = MAXV * MAXP * C;             // 8,000,000
static constexpr int NPV_OFF = CO_OFF + MAXV * 3;           // 8,480,000
static constexpr int VN_OFF  = NPV_OFF + MAXV;              // 8,640,000

typedef unsigned long long u64;
static constexpr u64 BYTEMUL = 0x0101010101010101ull;

// ---------------- shared phase bodies (used by mega kernel AND fallback) ----

__device__ __forceinline__ int dev_total(const float* vsz, const float* crg,
                                         int* pgy = nullptr, int* pgz = nullptr) {
    int gx = (int)rintf((crg[3] - crg[0]) / vsz[0]);
    int gy = (int)rintf((crg[4] - crg[1]) / vsz[1]);
    int gz = (int)rintf((crg[5] - crg[2]) / vsz[2]);
    if (pgy) *pgy = gy;
    if (pgz) *pgz = gz;
    return gx * gy * gz;
}

// quantize + pass-0 block histogram. hist row-major hist[b*RBUCK+d].
__device__ __forceinline__ void dev_linhist(const float* __restrict__ pts,
                                            const float* __restrict__ vsz,
                                            const float* __restrict__ crg,
                                            int* __restrict__ key0,
                                            int* __restrict__ hist,
                                            int NP, int b, int* __restrict__ sh) {
    int t = threadIdx.x;
    __syncthreads();                        // shm reuse guard
    for (int d = t; d < RBUCK; d += BLK) sh[d] = 0;
    float vx = vsz[0], vy = vsz[1], vz = vsz[2];
    float x0 = crg[0], y0 = crg[1], z0 = crg[2];
    int gx = (int)rintf((crg[3] - x0) / vx);
    int gy = (int)rintf((crg[4] - y0) / vy);
    int gz = (int)rintf((crg[5] - z0) / vz);
    int total = gx * gy * gz;
    __syncthreads();
    int base = b * ELEMS;
    #pragma unroll
    for (int r = 0; r < EPT; r++) {
        int i = base + r * BLK + t;
        if (i < NP) {
            float px = pts[i * C], py = pts[i * C + 1], pz = pts[i * C + 2];
            int cx = (int)floorf((px - x0) / vx);
            int cy = (int)floorf((py - y0) / vy);
            int cz = (int)floorf((pz - z0) / vz);
            bool valid = (cx >= 0) & (cx < gx) & (cy >= 0) & (cy < gy) & (cz >= 0) & (cz < gz);
            int k = valid ? (cx * gy + cy) * gz + cz : total;
            key0[i] = k;
            atomicAdd(&sh[k & (RBUCK - 1)], 1);
        }
    }
    __syncthreads();
    for (int d = t; d < RBUCK; d += BLK) hist[b * RBUCK + d] = sh[d];
}

// digit histogram over u64 pairs (high-32 keys)
__device__ __forceinline__ void dev_hist_p(const u64* __restrict__ pair,
                                           int* __restrict__ hist, int NP,
                                           int shift, int b, int* __restrict__ sh) {
    int t = threadIdx.x;
    __syncthreads();                        // shm reuse guard
    for (int d = t; d < RBUCK; d += BLK) sh[d] = 0;
    __syncthreads();
    int base = b * ELEMS;
    #pragma unroll
    for (int r = 0; r < EPT; r++) {
        int i = base + r * BLK + t;
        if (i < NP) atomicAdd(&sh[(int)((pair[i] >> (32 + shift)) & (RBUCK - 1))], 1);
    }
    __syncthreads();
    for (int d = t; d < RBUCK; d += BLK) hist[b * RBUCK + d] = sh[d];
}

// wave-per-digit exclusive scan across blocks (barrier-free)
__device__ __forceinline__ void dev_scanw(int* __restrict__ hist,
                                          int* __restrict__ dtot, int NB) {
    int wid = (blockIdx.x * BLK + threadIdx.x) >> 6;
    int lane = threadIdx.x & 63;
    int nw = (gridDim.x * BLK) >> 6;
    for (int d = wid; d < RBUCK; d += nw) {
        int carry = 0;
        for (int base = 0; base < NB; base += 64) {
            int b = base + lane;
            int v = (b < NB) ? hist[b * RBUCK + d] : 0;
            int x = v;
            #pragma unroll
            for (int o = 1; o < 64; o <<= 1) {
                int y = __shfl_up(x, o, 64);
                if (lane >= o) x += y;
            }
            if (b < NB) hist[b * RBUCK + d] = carry + x - v;   // exclusive
            carry += __shfl(x, 63, 64);
        }
        if (lane == 0) dtot[d] = carry;
    }
}

// stable scatter (proven r9 structure). shm needs 6*RBUCK ints.
__device__ __forceinline__ void dev_scat(const int* __restrict__ skey,
                                         const u64* __restrict__ spair,
                                         u64* __restrict__ dpair,
                                         const int* __restrict__ hist,
                                         const int* __restrict__ dtot,
                                         int NP, int shift, int b,
                                         int* __restrict__ shm) {
    int* cnt = shm;                     // RBUCK
    int* dbS = shm + RBUCK;             // RBUCK
    int* whistF = shm + 2 * RBUCK;      // 4*RBUCK; whist[w][d] = whistF[w*RBUCK+d]
    int t = threadIdx.x;
    int w = t >> 6, lane = t & 63;
    __syncthreads();                    // shm reuse guard
    if (t < 64) {
        int loc[8]; int run = 0;
        #pragma unroll
        for (int j = 0; j < 8; j++) { loc[j] = run; run += dtot[t * 8 + j]; }
        int tot = run;
        for (int o = 1; o < 64; o <<= 1) {
            int x = __shfl_up(tot, o, 64);
            if (lane >= o) tot += x;
        }
        int excl = tot - run;
        #pragma unroll
        for (int j = 0; j < 8; j++) dbS[t * 8 + j] = excl + loc[j];
    }
    for (int x = t; x < 4 * RBUCK; x += BLK) whistF[x] = -1;
    __syncthreads();
    for (int d = t; d < RBUCK; d += BLK) cnt[d] = dbS[d] + hist[b * RBUCK + d];
    __syncthreads();
    int base = b * ELEMS;
    int nc0 = 0, nc1 = 0; bool havenc = false;
    for (int r = 0; r < EPT; r++) {
        int i = base + r * BLK + t;
        bool act = i < NP;
        int k = 0, idx = 0, d = 0;
        if (act) {
            if (skey) { k = skey[i]; idx = i; }
            else { u64 pv = spair[i]; k = (int)(pv >> 32); idx = (int)(pv & 0xFFFFFFFFull); }
            d = (k >> shift) & (RBUCK - 1);
        }
        u64 m = __ballot(act);
        #pragma unroll
        for (int bit = 0; bit < RBITS; bit++) {
            u64 bb = __ballot(act && ((d >> bit) & 1));
            m &= ((d >> bit) & 1) ? bb : ~bb;
        }
        int rw = __popcll(m & ((1ull << lane) - 1ull));
        if (havenc) { cnt[t] = nc0; cnt[t + BLK] = nc1; }
        if (act && rw == 0) whistF[w * RBUCK + d] = (r << 20) | (int)__popcll(m);
        __syncthreads();
        if (act) {
            int off = cnt[d];
            for (int w2 = 0; w2 < w; w2++) {
                int e = whistF[w2 * RBUCK + d];
                off += ((e >> 20) == r) ? (e & 0xFFFFF) : 0;
            }
            dpair[off + rw] = ((u64)(uint32_t)k << 32) | (uint32_t)idx;
        }
        {
            int s0 = 0, s1 = 0;
            #pragma unroll
            for (int w2 = 0; w2 < 4; w2++) {
                int e0 = whistF[w2 * RBUCK + t];
                int e1 = whistF[w2 * RBUCK + t + BLK];
                s0 += ((e0 >> 20) == r) ? (e0 & 0xFFFFF) : 0;
                s1 += ((e1 >> 20) == r) ? (e1 & 0xFFFFF) : 0;
            }
            nc0 = cnt[t] + s0; nc1 = cnt[t + BLK] + s1; havenc = true;
        }
        __syncthreads();
    }
    __syncthreads();
}

// per-block packed head/valid sums braw[b]=(h<<16)|v. shm needs 2*BLK ints.
__device__ __forceinline__ void dev_heads(const u64* __restrict__ pair,
                                          int* __restrict__ braw, int TOTAL,
                                          int NP, int b, int* __restrict__ shm) {
    int* sh = shm; int* sv = shm + BLK;
    int t = threadIdx.x;
    int sbase = b * ELEMS + t * EPT;
    int hs = 0, vs = 0;
    if (sbase < NP) {
        int kprev = (sbase == 0) ? -1 : (int)(pair[sbase - 1] >> 32);
        #pragma unroll
        for (int r = 0; r < EPT; r++) {
            int i = sbase + r;
            if (i < NP) {
                int k = (int)(pair[i] >> 32);
                if (k != TOTAL) { vs++; hs += (k != kprev); }
                kprev = k;
            }
        }
    }
    __syncthreads();                    // shm reuse guard
    sh[t] = hs; sv[t] = vs;
    __syncthreads();
    for (int o = BLK / 2; o > 0; o >>= 1) {
        if (t < o) { sh[t] += sh[t + o]; sv[t] += sv[t + o]; }
        __syncthreads();
    }
    if (t == 0) braw[b] = (sh[0] << 16) | sv[0];
}

// braw prefix walk + gstart/ghead/flags emit. shm needs BLK ints + eS scalar.
__device__ __forceinline__ void dev_heads2(const u64* __restrict__ pair,
        const int* __restrict__ braw, int* __restrict__ bsumH,
        int* __restrict__ gstart, int* __restrict__ ghead,
        u64* __restrict__ flags8, int* __restrict__ ctrl,
        float* __restrict__ out_vnum, int TOTAL, int NP, int NB, int b,
        int* __restrict__ s, int* __restrict__ eSp) {
    int t = threadIdx.x;
    __syncthreads();                    // shm/eS reuse guard
    if (t < 64) {
        int eh = 0, ev = 0;
        for (int base = 0; base < b; base += 64) {
            int idx = base + t;
            int pb = (idx < b) ? braw[idx] : 0;
            int hh = (pb >> 16) & 0xFFFF, vv = pb & 0xFFFF;
            #pragma unroll
            for (int o = 32; o > 0; o >>= 1) {
                hh += __shfl_down(hh, o, 64);
                vv += __shfl_down(vv, o, 64);
            }
            eh += hh; ev += vv;         // meaningful on lane 0
        }
        if (t == 0) {
            *eSp = eh;
            bsumH[b] = eh;
            if (b == NB - 1) {
                int own = braw[b];
                int G = eh + ((own >> 16) & 0xFFFF);
                int nval = ev + (own & 0xFFFF);
                ctrl[0] = G; ctrl[1] = nval;
                out_vnum[0] = (float)(G < MAXV ? G : MAXV);
            }
        }
    }
    int sbase = b * ELEMS + t * EPT;
    u64 pv[EPT];
    int hcnt = 0;
    unsigned hbits = 0;
    if (sbase < NP) {
        int kprev = (sbase == 0) ? -1 : (int)(pair[sbase - 1] >> 32);
        #pragma unroll
        for (int r = 0; r < EPT; r++) {
            int i = sbase + r;
            if (i < NP) {
                pv[r] = pair[i];
                int k = (int)(pv[r] >> 32);
                int h = (k != TOTAL) && (k != kprev);
                hbits |= (unsigned)h << r;
                hcnt += h;
                kprev = k;
            }
        }
    }
    s[t] = hcnt;
    __syncthreads();                    // also publishes eS
    for (int o = 1; o < BLK; o <<= 1) {
        int x = (t >= o) ? s[t - o] : 0; __syncthreads();
        s[t] += x; __syncthreads();
    }
    if (sbase < NP && hbits) {
        int g = *eSp + s[t] - hcnt;
        unsigned char* flags = (unsigned char*)flags8;
        #pragma unroll
        for (int r = 0; r < EPT; r++) {
            if ((hbits >> r) & 1) {
                gstart[g] = sbase + r;
                int io = (int)(pv[r] & 0xFFFFFFFFull);
                ghead[g] = io;
                flags[io] = 1;
                g++;
            }
        }
    }
}

__device__ __forceinline__ void dev_wpA(const u64* __restrict__ flags8,
                                        int* __restrict__ wsum, int NP8,
                                        int b, int* __restrict__ s) {
    int t = threadIdx.x, i = b * BLK + t;
    u64 wv = (i < NP8) ? flags8[i] : 0ull;
    __syncthreads();                    // shm reuse guard
    s[t] = (int)((wv * BYTEMUL) >> 56);
    __syncthreads();
    for (int o = BLK / 2; o > 0; o >>= 1) { if (t < o) s[t] += s[t + o]; __syncthreads(); }
    if (t == 0) wsum[b] = s[0];
}

__device__ __forceinline__ void dev_wp2(const u64* __restrict__ flags8,
                                        const int* __restrict__ wsum,
                                        int* __restrict__ wpfx, int NP8,
                                        int b, int* __restrict__ s,
                                        int* __restrict__ eSp) {
    int t = threadIdx.x;
    __syncthreads();                    // shm/eS reuse guard
    if (t < 64) {
        int acc = 0;
        for (int base = 0; base < b; base += 64) {
            int idx = base + t;
            int v = (idx < b) ? wsum[idx] : 0;
            #pragma unroll
            for (int o = 32; o > 0; o >>= 1) v += __shfl_down(v, o, 64);
            acc += v;
        }
        if (t == 0) *eSp = acc;
    }
    int i = b * BLK + t;
    u64 wv = (i < NP8) ? flags8[i] : 0ull;
    int v = (int)((wv * BYTEMUL) >> 56);
    s[t] = v;
    __syncthreads();                    // also publishes eS
    for (int o = 1; o < BLK; o <<= 1) {
        int x = (t >= o) ? s[t - o] : 0; __syncthreads();
        s[t] += x; __syncthreads();
    }
    if (i < NP8) wpfx[i] = *eSp + s[t] - v;
}

__device__ __forceinline__ int vox_rank(const u64* flags8, const int* wpfx, int io) {
    int w = io >> 3, b8 = io & 7;
    u64 below = flags8[w] & ((1ull << (8 * b8)) - 1ull);
    return wpfx[w] + (int)((below * BYTEMUL) >> 56);
}

// fused emit. shm needs BLK ints.
__device__ __forceinline__ void dev_emit(const u64* __restrict__ pair,
        const int* __restrict__ gstart, const int* __restrict__ ghead,
        const u64* __restrict__ flags8, const int* __restrict__ wpfx,
        int G, int nval, int TOTAL, int gyd, int gzd,
        const int* __restrict__ bsumH, const float* __restrict__ pts,
        float* __restrict__ out, int NP, int b, int* __restrict__ s) {
    int t = threadIdx.x;
    int sbase = b * ELEMS + t * EPT;
    u64 pv[EPT];
    int hcnt = 0;
    unsigned hbits = 0;
    if (sbase < NP) {
        int kprev = (sbase == 0) ? -1 : (int)(pair[sbase - 1] >> 32);
        #pragma unroll
        for (int r = 0; r < EPT; r++) {
            int i = sbase + r;
            if (i < NP) {
                pv[r] = pair[i];
                int k = (int)(pv[r] >> 32);
                int h = (k != TOTAL) && (k != kprev);
                hbits |= (unsigned)h << r;
                hcnt += h;
                kprev = k;
            }
        }
    }
    __syncthreads();                    // shm reuse guard
    s[t] = hcnt;
    __syncthreads();
    for (int o = 1; o < BLK; o <<= 1) {
        int x = (t >= o) ? s[t - o] : 0; __syncthreads();
        s[t] += x; __syncthreads();
    }
    if (sbase < NP) {
        int ggi = bsumH[b] + (s[t] - hcnt) - 1;   // group of element BEFORE chunk
        int cgg = -2, cvid = 0, cp0 = 0;          // per-thread group cache
        #pragma unroll
        for (int r = 0; r < EPT; r++) {
            int i = sbase + r;
            if (i >= NP) break;
            int h = (hbits >> r) & 1;
            ggi += h;
            u64 p = pv[r];
            int k = (int)(p >> 32);
            if (k == TOTAL) continue;             // sorted suffix of invalids
            if (ggi != cgg) {
                cgg = ggi;
                cp0 = gstart[ggi];
                cvid = vox_rank(flags8, wpfx, ghead[ggi]);
            }
            int p0 = cp0, vid = cvid;
            if (vid >= MAXV) continue;
            if (h) {                              // per-voxel work (once per group)
                int cz = k % gzd; int rr = k / gzd; int cy = rr % gyd; int cx = rr / gyd;
                out[CO_OFF + vid * 3 + 0] = (float)cz;
                out[CO_OFF + vid * 3 + 1] = (float)cy;
                out[CO_OFF + vid * 3 + 2] = (float)cx;
                int nxt = (ggi + 1 < G) ? gstart[ggi + 1] : nval;
                int gsz = nxt - p0;
                out[NPV_OFF + vid] = (float)(gsz < MAXP ? gsz : MAXP);
            }
            int slot = i - p0;
            if (slot >= MAXP) continue;
            int iorig = (int)(p & 0xFFFFFFFFull);
            const float* src = pts + iorig * C;
            float* dst = out + (vid * MAXP + slot) * C;
            dst[0] = src[0]; dst[1] = src[1]; dst[2] = src[2]; dst[3] = src[3]; dst[4] = src[4];
        }
    }
}

// ---------------- mega kernel: whole pipeline, 13 grid syncs ----------------
// __launch_bounds__(256,3): 3 blocks/CU guaranteed -> coop capacity >= 768 >= NB.
__global__ void __launch_bounds__(BLK, 3) kv15_mega(
        const float* pts, const float* vsz, const float* crg, float* out,
        u64* pairA, u64* pairB, int* hist, u64* flags8, int* braw, int* bsumH,
        int* dtot, int* wpfx, int* wsum, int* ctrl, int NP, int NB, int NP8) {
    cg::grid_group gridg = cg::this_grid();
    __shared__ int shm[6 * RBUCK];     // 12,288 B: max over phase needs
    __shared__ int eS;
    int* key0   = (int*)pairB;         // aliases pairB (dead before pass-1 write)
    int* gstart = (int*)pairB;         // pairB free after pass 2
    int* ghead  = gstart + NP;

    // Phase A: quantize + pass-0 hist; zero output + flags8
    for (int vb = blockIdx.x; vb < NB; vb += gridDim.x)
        dev_linhist(pts, vsz, crg, key0, hist, NP, vb, shm);
    {
        int tid = blockIdx.x * BLK + threadIdx.x, nth = gridDim.x * BLK;
        float4* out4 = (float4*)out;
        const float4 z4 = make_float4(0.f, 0.f, 0.f, 0.f);
        for (int i = tid; i < VN_OFF / 4; i += nth) out4[i] = z4;
        for (int i = tid; i < NP8; i += nth) flags8[i] = 0ull;
    }
    gridg.sync();
    // Pass 0: key0 -> pairA
    dev_scanw(hist, dtot, NB);
    gridg.sync();
    for (int vb = blockIdx.x; vb < NB; vb += gridDim.x)
        dev_scat(key0, nullptr, pairA, hist, dtot, NP, 0, vb, shm);
    gridg.sync();
    // Pass 1: pairA -> pairB (clobbers key0 — dead)
    for (int vb = blockIdx.x; vb < NB; vb += gridDim.x)
        dev_hist_p(pairA, hist, NP, RBITS, vb, shm);
    gridg.sync();
    dev_scanw(hist, dtot, NB);
    gridg.sync();
    for (int vb = blockIdx.x; vb < NB; vb += gridDim.x)
        dev_scat(nullptr, pairA, pairB, hist, dtot, NP, RBITS, vb, shm);
    gridg.sync();
    // Pass 2: pairB -> pairA (final sorted order)
    for (int vb = blockIdx.x; vb < NB; vb += gridDim.x)
        dev_hist_p(pairB, hist, NP, 2 * RBITS, vb, shm);
    gridg.sync();
    dev_scanw(hist, dtot, NB);
    gridg.sync();
    for (int vb = blockIdx.x; vb < NB; vb += gridDim.x)
        dev_scat(nullptr, pairB, pairA, hist, dtot, NP, 2 * RBITS, vb, shm);
    gridg.sync();

    int gyd, gzd;
    int TOTAL = dev_total(vsz, crg, &gyd, &gzd);

    for (int vb = blockIdx.x; vb < NB; vb += gridDim.x)
        dev_heads(pairA, braw, TOTAL, NP, vb, shm);
    gridg.sync();
    for (int vb = blockIdx.x; vb < NB; vb += gridDim.x)
        dev_heads2(pairA, braw, bsumH, gstart, ghead, flags8, ctrl,
                   out + VN_OFF, TOTAL, NP, NB, vb, shm, &eS);
    gridg.sync();
    for (int wb = blockIdx.x; wb < NB; wb += gridDim.x)   // NWB == NB (2048=8*256)
        dev_wpA(flags8, wsum, NP8, wb, shm);
    gridg.sync();
    for (int wb = blockIdx.x; wb < NB; wb += gridDim.x)
        dev_wp2(flags8, wsum, wpfx, NP8, wb, shm, &eS);
    gridg.sync();
    int G = ctrl[0], nval = ctrl[1];
    for (int vb = blockIdx.x; vb < NB; vb += gridDim.x)
        dev_emit(pairA, gstart, ghead, flags8, wpfx, G, nval, TOTAL, gyd, gzd,
                 bsumH, pts, out, NP, vb, shm);
}

// ---------------- fallback wrappers (15-dispatch path, r2-proven) -----------

__global__ void fb_linhist(const float* pts, const float* vsz, const float* crg,
                           int* key0, int* hist, int NP) {
    __shared__ int shm[RBUCK];
    dev_linhist(pts, vsz, crg, key0, hist, NP, blockIdx.x, shm);
}
__global__ void fb_zero(float4* a, int n, float4* b, int m) {
    int i = blockIdx.x * BLK + threadIdx.x;
    float4 z = make_float4(0.f, 0.f, 0.f, 0.f);
    if (i < n) a[i] = z;
    else { int j = i - n; if (j < m) b[j] = z; }
}
__global__ void fb_scanw(int* hist, int* dtot, int NB) { dev_scanw(hist, dtot, NB); }
__global__ void fb_scat0(const int* key0, u64* dpair, const int* hist,
                         const int* dtot, int NP) {
    __shared__ int shm[6 * RBUCK];
    dev_scat(key0, nullptr, dpair, hist, dtot, NP, 0, blockIdx.x, shm);
}
__global__ void fb_scatp(const u64* spair, u64* dpair, const int* hist,
                         const int* dtot, int NP, int shift) {
    __shared__ int shm[6 * RBUCK];
    dev_scat(nullptr, spair, dpair, hist, dtot, NP, shift, blockIdx.x, shm);
}
__global__ void fb_histp(const u64* pair, int* hist, int NP, int shift) {
    __shared__ int shm[RBUCK];
    dev_hist_p(pair, hist, NP, shift, blockIdx.x, shm);
}
__global__ void fb_heads(const u64* pair, int* braw, const float* vsz,
                         const float* crg, int NP) {
    __shared__ int shm[2 * BLK];
    dev_heads(pair, braw, dev_total(vsz, crg), NP, blockIdx.x, shm);
}
__global__ void fb_heads2(const u64* pair, const int* braw, int* bsumH,
                          int* gstart, int* ghead, u64* flags8, int* ctrl,
                          float* out_vnum, const float* vsz, const float* crg,
                          int NP, int NB) {
    __shared__ int shm[BLK];
    __shared__ int eS;
    dev_heads2(pair, braw, bsumH, gstart, ghead, flags8, ctrl, out_vnum,
               dev_total(vsz, crg), NP, NB, blockIdx.x, shm, &eS);
}
__global__ void fb_wpA(const u64* flags8, int* wsum, int NP8) {
    __shared__ int shm[BLK];
    dev_wpA(flags8, wsum, NP8, blockIdx.x, shm);
}
__global__ void fb_wp2(const u64* flags8, const int* wsum, int* wpfx, int NP8) {
    __shared__ int shm[BLK];
    __shared__ int eS;
    dev_wp2(flags8, wsum, wpfx, NP8, blockIdx.x, shm, &eS);
}
__global__ void fb_emit(const u64* pair, const int* gstart, const int* ghead,
                        const u64* flags8, const int* wpfx, const int* ctrl,
                        const int* bsumH, const float* pts, const float* vsz,
                        const float* crg, float* out, int NP) {
    __shared__ int shm[BLK];
    int gyd, gzd;
    int TOTAL = dev_total(vsz, crg, &gyd, &gzd);
    dev_emit(pair, gstart, ghead, flags8, wpfx, ctrl[0], ctrl[1], TOTAL, gyd,
             gzd, bsumH, pts, out, NP, blockIdx.x, shm);
}

// ---------------- launch ----------------------------------------------------

extern "C" void kernel_launch(void* const* d_in, const int* in_sizes, int n_in,
                              void* d_out, int out_size, void* d_ws, size_t ws_size,
                              hipStream_t stream) {
    if (!d_out || !d_ws || n_in < 3) return;
    const float* pts = (const float*)d_in[0];
    const float* vsz = (const float*)d_in[1];
    const float* crg = (const float*)d_in[2];
    if (!pts || !vsz || !crg) return;
    int NP = in_sizes[0] / C;
    if (NP <= 0) return;
    int NB  = (NP + ELEMS - 1) / ELEMS;           // 2048-elem blocks (586)
    int NP8 = (NP + 7) / 8;                       // byte-flag u64 words (150000)

    size_t need = 2ull * NP * 8ull                          // pairA + pairB
                + (size_t)RBUCK * NB * 4ull                 // hist
                + (size_t)NP8 * 8ull                        // flags8
                + 2ull * NB * 4ull                          // braw, bsumH
                + (size_t)RBUCK * 4ull                      // dtot
                + (size_t)NP8 * 4ull                        // wpfx
                + (size_t)NB * 4ull + 8ull * 4ull;          // wsum, ctrl
    if (ws_size < need) return;
    if ((size_t)out_size < (size_t)VN_OFF + 1) return;

    u64* pairA  = (u64*)d_ws;
    u64* pairB  = pairA + NP;
    int* hist   = (int*)(pairB + NP);
    u64* flags8 = (u64*)(hist + (size_t)RBUCK * NB);
    int* w      = (int*)(flags8 + NP8);
    int* braw  = w; w += NB;
    int* bsumH = w; w += NB;
    int* dtot  = w; w += RBUCK;
    int* wpfx  = w; w += NP8;
    int* wsum  = w; w += NB;
    int* ctrl  = w; w += 8;
    float* out = (float*)d_out;

    // co-resident capacity for the cooperative launch (cached; host-side pure queries)
    static int gridCap = 0;
    if (gridCap == 0) {
        int perCU = 0;
        if (hipOccupancyMaxActiveBlocksPerMultiprocessor(&perCU, kv15_mega, BLK, 0)
                != hipSuccess || perCU <= 0)
            perCU = 2;
        int nCU = 256, dev = 0;
        hipDeviceProp_t prop;
        if (hipGetDevice(&dev) == hipSuccess &&
            hipGetDeviceProperties(&prop, dev) == hipSuccess &&
            prop.multiProcessorCount > 0)
            nCU = prop.multiProcessorCount;
        gridCap = perCU * nCU;
    }
    int grid = NB < gridCap ? NB : gridCap;

    void* args[] = { &pts, &vsz, &crg, &out, &pairA, &pairB, &hist, &flags8,
                     &braw, &bsumH, &dtot, &wpfx, &wsum, &ctrl, &NP, &NB, &NP8 };
    hipError_t err = hipLaunchCooperativeKernel((void*)kv15_mega, dim3(grid),
                                                dim3(BLK), args, 0, stream);
    if (err == hipSuccess) return;

    // -------- fallback: proven 15-dispatch pipeline --------
    int* key0   = (int*)pairB;
    int* gstart = (int*)pairB;
    int* ghead  = gstart + NP;
    const int n4 = VN_OFF / 4;
    const int m4 = (int)((size_t)NP8 * 8ull / 16ull);

    fb_linhist<<<NB, BLK, 0, stream>>>(pts, vsz, crg, key0, hist, NP);
    fb_zero<<<(n4 + m4 + BLK - 1) / BLK, BLK, 0, stream>>>((float4*)out, n4,
                                                           (float4*)flags8, m4);
    fb_scanw<<<RBUCK / 4, BLK, 0, stream>>>(hist, dtot, NB);
    fb_scat0<<<NB, BLK, 0, stream>>>(key0, pairA, hist, dtot, NP);
    fb_histp<<<NB, BLK, 0, stream>>>(pairA, hist, NP, RBITS);
    fb_scanw<<<RBUCK / 4, BLK, 0, stream>>>(hist, dtot, NB);
    fb_scatp<<<NB, BLK, 0, stream>>>(pairA, pairB, hist, dtot, NP, RBITS);
    fb_histp<<<NB, BLK, 0, stream>>>(pairB, hist, NP, 2 * RBITS);
    fb_scanw<<<RBUCK / 4, BLK, 0, stream>>>(hist, dtot, NB);
    fb_scatp<<<NB, BLK, 0, stream>>>(pairB, pairA, hist, dtot, NP, 2 * RBITS);
    fb_heads<<<NB, BLK, 0, stream>>>(pairA, braw, vsz, crg, NP);
    fb_heads2<<<NB, BLK, 0, stream>>>(pairA, braw, bsumH, gstart, ghead, flags8,
                                      ctrl, out + VN_OFF, vsz, crg, NP, NB);
    fb_wpA<<<NB, BLK, 0, stream>>>(flags8, wsum, NP8);
    fb_wp2<<<NB, BLK, 0, stream>>>(flags8, wsum, wpfx, NP8);
    fb_emit<<<NB, BLK, 0, stream>>>(pairA, gstart, ghead, flags8, wpfx, ctrl,
                                    bsumH, pts, vsz, crg, out, NP);
}

// Round 4
// 204.023 us; speedup vs baseline: 5.7463x; 5.7463x over previous
//
#include <hip/hip_runtime.h>
#include <cstdint>

static constexpr int C     = 5;
static constexpr int MAXP  = 10;
static constexpr int MAXV  = 160000;
static constexpr int BLK   = 256;
static constexpr int RB    = 2048;         // hash buckets
static constexpr int BCAP  = 1024;         // bucket capacity for LDS sort (lambda~571 + 8 sigma)
static constexpr int EPT   = 8;
static constexpr int ELEMS = BLK * EPT;    // 2048 elements per block

// Output layout (float32, concatenated in reference return order)
static constexpr int VOX_OFF = 0;                           // 160000*10*5
static constexpr int CO_OFF  = MAXV * MAXP * C;             // 8,000,000
static constexpr int NPV_OFF = CO_OFF + MAXV * 3;           // 8,480,000
static constexpr int VN_OFF  = NPV_OFF + MAXV;              // 8,640,000

typedef unsigned long long u64;
static constexpr u64 BYTEMUL = 0x0101010101010101ull;

// Injective partition: equal lins always share a bucket; inter-bucket order is
// irrelevant (vid comes from first-appearance rank via flags, not sort order).
__device__ __forceinline__ int hashb(int k) {
    return (int)(((uint32_t)k * 2654435761u) >> 21);        // 11 bits -> [0,2048)
}

// K1: quantize -> key0 (-1 = invalid), per-block bucket histogram,
// fused zero-fill of output + flags8 (grid-stride).
__global__ void vx_prep(const float* __restrict__ pts, const float* __restrict__ vsz,
                        const float* __restrict__ crg, int* __restrict__ key0,
                        int* __restrict__ hist, u64* __restrict__ flags8,
                        float* __restrict__ out, int NP, int NP8) {
    __shared__ int sh[RB];
    int t = threadIdx.x, b = blockIdx.x;
    for (int d = t; d < RB; d += BLK) sh[d] = 0;
    float vx = vsz[0], vy = vsz[1], vz = vsz[2];
    float x0 = crg[0], y0 = crg[1], z0 = crg[2];
    int gx = (int)rintf((crg[3] - x0) / vx);
    int gy = (int)rintf((crg[4] - y0) / vy);
    int gz = (int)rintf((crg[5] - z0) / vz);
    __syncthreads();
    int base = b * ELEMS;
    #pragma unroll
    for (int r = 0; r < EPT; r++) {
        int i = base + r * BLK + t;
        if (i < NP) {
            float px = pts[i * C], py = pts[i * C + 1], pz = pts[i * C + 2];
            int cx = (int)floorf((px - x0) / vx);
            int cy = (int)floorf((py - y0) / vy);
            int cz = (int)floorf((pz - z0) / vz);
            bool valid = (cx >= 0) & (cx < gx) & (cy >= 0) & (cy < gy) & (cz >= 0) & (cz < gz);
            int k = (cx * gy + cy) * gz + cz;
            key0[i] = valid ? k : -1;
            if (valid) atomicAdd(&sh[hashb(k)], 1);
        }
    }
    __syncthreads();
    for (int d = t; d < RB; d += BLK) hist[b * RB + d] = sh[d];
    // fused zero-fill (out is float4-aligned; VN_OFF divisible by 4)
    int tid = b * BLK + t, nth = gridDim.x * BLK;
    float4* out4 = (float4*)out;
    const float4 z4 = make_float4(0.f, 0.f, 0.f, 0.f);
    for (int i = tid; i < VN_OFF / 4; i += nth) out4[i] = z4;
    for (int i = tid; i < NP8; i += nth) flags8[i] = 0ull;
}

// K2: wave-per-bucket exclusive scan across blocks (grid = RB/4 = 512).
__global__ void vx_scanw(int* __restrict__ hist, int* __restrict__ dtot, int NB) {
    int t = threadIdx.x;
    int lane = t & 63;
    int d = blockIdx.x * 4 + (t >> 6);
    int carry = 0;
    for (int base = 0; base < NB; base += 64) {
        int b = base + lane;
        int v = (b < NB) ? hist[b * RB + d] : 0;
        int x = v;
        #pragma unroll
        for (int o = 1; o < 64; o <<= 1) {
            int y = __shfl_up(x, o, 64);
            if (lane >= o) x += y;
        }
        if (b < NB) hist[b * RB + d] = carry + x - v;        // exclusive
        carry += __shfl(x, 63, 64);
    }
    if (lane == 0) dtot[d] = carry;
}

// K3: UNSTABLE bucket scatter (LDS-atomic slot grab). Stability is restored by
// the per-bucket (k,idx)-u64 sort in vx_bsort — so no ballot/whist machinery.
// Invalid points (key0 < 0) are dropped here; buckets are tightly packed.
__global__ void vx_scat(const int* __restrict__ key0, const int* __restrict__ hist,
                        const int* __restrict__ dtot, u64* __restrict__ pairA, int NP) {
    __shared__ int cnt[RB];
    int t = threadIdx.x, b = blockIdx.x;
    int lane = t & 63;
    if (t < 64) {                           // cross-bucket bases: 32 buckets/lane
        int loc[32]; int run = 0;
        #pragma unroll
        for (int j = 0; j < 32; j++) { loc[j] = run; run += dtot[t * 32 + j]; }
        int tot = run;
        for (int o = 1; o < 64; o <<= 1) {
            int x = __shfl_up(tot, o, 64);
            if (lane >= o) tot += x;
        }
        int excl = tot - run;
        #pragma unroll
        for (int j = 0; j < 32; j++) cnt[t * 32 + j] = excl + loc[j];
    }
    __syncthreads();
    for (int d = t; d < RB; d += BLK) cnt[d] += hist[b * RB + d];
    __syncthreads();
    int base = b * ELEMS;
    #pragma unroll
    for (int r = 0; r < EPT; r++) {
        int i = base + r * BLK + t;
        if (i < NP) {
            int k = key0[i];
            if (k >= 0) {
                int pos = atomicAdd(&cnt[hashb(k)], 1);
                pairA[pos] = ((u64)(uint32_t)k << 32) | (uint32_t)i;
            }
        }
    }
}

// K4: per-bucket in-LDS bitonic sort of u64 (k,idx) pairs (canonical order:
// groups contiguous, idx-ascending within group) + head-flag emission.
// A lin lives in exactly one bucket, so bucket-local head detection is exact.
__global__ void __launch_bounds__(512) vx_bsort(u64* __restrict__ pairA,
                                                const int* __restrict__ dtot,
                                                u64* __restrict__ flags8) {
    __shared__ u64 sp[BCAP];
    __shared__ int sb[2];
    int t = threadIdx.x, d = blockIdx.x;
    if (t < 64) {                           // start = sum dtot[0..d)
        int acc = 0;
        for (int j = t; j < d; j += 64) acc += dtot[j];
        #pragma unroll
        for (int o = 32; o > 0; o >>= 1) acc += __shfl_down(acc, o, 64);
        if (t == 0) { sb[0] = acc; sb[1] = dtot[d]; }
    }
    __syncthreads();
    int start = sb[0], size = sb[1];
    if (size <= 0) return;                  // uniform per block
    if (size > BCAP) size = BCAP;           // statistically unreachable guard
    for (int i = t; i < BCAP; i += 512) sp[i] = (i < size) ? pairA[start + i] : ~0ull;
    __syncthreads();
    for (int k2 = 2; k2 <= BCAP; k2 <<= 1) {
        for (int j = k2 >> 1; j > 0; j >>= 1) {
            int lo = t & (j - 1);
            int i  = ((t ^ lo) << 1) | lo;  // bit j of i is 0
            int ix = i | j;
            u64 a = sp[i], c = sp[ix];
            bool up = (i & k2) == 0;
            if ((a > c) == up) { sp[i] = c; sp[ix] = a; }
            __syncthreads();
        }
    }
    unsigned char* flags = (unsigned char*)flags8;
    for (int i = t; i < size; i += 512) {
        u64 p = sp[i];
        pairA[start + i] = p;
        bool head = (i == 0) || ((p >> 32) != (sp[i - 1] >> 32));
        if (head) flags[(uint32_t)(p & 0xFFFFFFFFull)] = 1;
    }
}

// K5: per-block bytesum of flag words (publishes partials for wp2's walk).
__global__ void vx_wpA(const u64* __restrict__ flags8, int* __restrict__ wsum, int NP8) {
    __shared__ int s[BLK];
    int t = threadIdx.x, i = blockIdx.x * BLK + t;
    u64 wv = (i < NP8) ? flags8[i] : 0ull;
    s[t] = (int)((wv * BYTEMUL) >> 56);
    __syncthreads();
    for (int o = BLK / 2; o > 0; o >>= 1) { if (t < o) s[t] += s[t + o]; __syncthreads(); }
    if (t == 0) wsum[blockIdx.x] = s[0];
}

// K6: no-spin walk over wsum + in-block scan -> wpfx; last block writes voxel_num
// (G = total head count = total flag bytes).
__global__ void vx_wp2(const u64* __restrict__ flags8, const int* __restrict__ wsum,
                       int* __restrict__ wpfx, float* __restrict__ out_vnum, int NP8) {
    __shared__ int s[BLK];
    __shared__ int eS;
    int t = threadIdx.x, b = blockIdx.x;
    if (t < 64) {
        int acc = 0;
        for (int base = 0; base < b; base += 64) {
            int idx = base + t;
            int v = (idx < b) ? wsum[idx] : 0;
            #pragma unroll
            for (int o = 32; o > 0; o >>= 1) v += __shfl_down(v, o, 64);
            acc += v;
        }
        if (t == 0) eS = acc;
    }
    int i = b * BLK + t;
    u64 wv = (i < NP8) ? flags8[i] : 0ull;
    int v = (int)((wv * BYTEMUL) >> 56);
    s[t] = v;
    __syncthreads();                        // also publishes eS
    for (int o = 1; o < BLK; o <<= 1) {
        int x = (t >= o) ? s[t - o] : 0; __syncthreads();
        s[t] += x; __syncthreads();
    }
    if (i < NP8) wpfx[i] = eS + s[t] - v;
    if (b == gridDim.x - 1 && t == BLK - 1) {
        int G = eS + s[t];
        out_vnum[0] = (float)(G < MAXV ? G : MAXV);
    }
}

__device__ __forceinline__ int vox_rank(const u64* flags8, const int* wpfx, int io) {
    int w = io >> 3, b8 = io & 7;
    u64 below = flags8[w] & ((1ull << (8 * b8)) - 1ull);
    return wpfx[w] + (int)((below * BYTEMUL) >> 56);
}

// K7: bucket-geometry emit. Group start/end are bucket-local (gpos), vid via
// flags-rank of the head's original index. No gstart/ghead/ctrl arrays needed.
__global__ void vx_emit(const u64* __restrict__ pairA, const int* __restrict__ dtot,
                        const u64* __restrict__ flags8, const int* __restrict__ wpfx,
                        const float* __restrict__ pts, const float* __restrict__ vsz,
                        const float* __restrict__ crg, float* __restrict__ out) {
    __shared__ u64 sp[BCAP];
    __shared__ int gpos[BCAP + 1];
    __shared__ int s[BLK];
    __shared__ int sb[2];
    int t = threadIdx.x, d = blockIdx.x;
    if (t < 64) {
        int acc = 0;
        for (int j = t; j < d; j += 64) acc += dtot[j];
        #pragma unroll
        for (int o = 32; o > 0; o >>= 1) acc += __shfl_down(acc, o, 64);
        if (t == 0) { sb[0] = acc; sb[1] = dtot[d]; }
    }
    __syncthreads();
    int start = sb[0], size = sb[1];
    if (size <= 0) return;
    if (size > BCAP) size = BCAP;
    for (int i = t; i < size; i += BLK) sp[i] = pairA[start + i];
    __syncthreads();
    const int EL = BCAP / BLK;              // 4 local elements per thread
    int i0 = t * EL;
    unsigned hbits = 0; int hcnt = 0;
    #pragma unroll
    for (int r = 0; r < EL; r++) {
        int i = i0 + r;
        if (i < size) {
            int k = (int)(sp[i] >> 32);
            int h = (i == 0) || (k != (int)(sp[i - 1] >> 32));
            hbits |= (unsigned)h << r;
            hcnt += h;
        }
    }
    s[t] = hcnt;
    __syncthreads();
    for (int o = 1; o < BLK; o <<= 1) {
        int x = (t >= o) ? s[t - o] : 0; __syncthreads();
        s[t] += x; __syncthreads();
    }
    int gbase = s[t] - hcnt;                // heads before this thread's chunk
    {
        int g = gbase;
        #pragma unroll
        for (int r = 0; r < EL; r++)
            if ((hbits >> r) & 1) gpos[g++] = i0 + r;
    }
    int NG = s[BLK - 1];                    // total groups in bucket (>=1)
    if (t == 0) gpos[NG] = size;
    __syncthreads();
    int gyd = (int)rintf((crg[4] - crg[1]) / vsz[1]);
    int gzd = (int)rintf((crg[5] - crg[2]) / vsz[2]);
    int gg = gbase - 1;                     // group of element before chunk
    int cgg = -2, cvid = 0, cp0 = 0, cp1 = 0;
    #pragma unroll
    for (int r = 0; r < EL; r++) {
        int i = i0 + r;
        if (i >= size) break;
        int h = (hbits >> r) & 1;
        gg += h;
        u64 p = sp[i];
        int k = (int)(p >> 32);
        if (gg != cgg) {
            cgg = gg;
            cp0 = gpos[gg];
            cp1 = gpos[gg + 1];
            cvid = vox_rank(flags8, wpfx, (int)(sp[cp0] & 0xFFFFFFFFull));
        }
        if (cvid >= MAXV) continue;
        if (h) {                            // per-voxel work (once per group)
            int cz = k % gzd; int rr = k / gzd; int cy = rr % gyd; int cx = rr / gyd;
            out[CO_OFF + cvid * 3 + 0] = (float)cz;
            out[CO_OFF + cvid * 3 + 1] = (float)cy;
            out[CO_OFF + cvid * 3 + 2] = (float)cx;
            int gsz = cp1 - cp0;
            out[NPV_OFF + cvid] = (float)(gsz < MAXP ? gsz : MAXP);
        }
        int slot = i - cp0;
        if (slot >= MAXP) continue;
        int io = (int)(p & 0xFFFFFFFFull);
        const float* src = pts + io * C;
        float* dst = out + (cvid * MAXP + slot) * C;
        dst[0] = src[0]; dst[1] = src[1]; dst[2] = src[2]; dst[3] = src[3]; dst[4] = src[4];
    }
}

extern "C" void kernel_launch(void* const* d_in, const int* in_sizes, int n_in,
                              void* d_out, int out_size, void* d_ws, size_t ws_size,
                              hipStream_t stream) {
    if (!d_out || !d_ws || n_in < 3) return;
    const float* pts = (const float*)d_in[0];
    const float* vsz = (const float*)d_in[1];
    const float* crg = (const float*)d_in[2];
    if (!pts || !vsz || !crg) return;
    const int NP  = in_sizes[0] / C;
    if (NP <= 0) return;
    const int NB  = (NP + ELEMS - 1) / ELEMS;     // 2048-elem blocks (586)
    const int NP8 = (NP + 7) / 8;                 // byte-flag u64 words (150000)
    const int NWB = (NP8 + BLK - 1) / BLK;        // wp blocks (586)

    size_t need = (size_t)NP * 8ull                         // pairA
                + (size_t)NP * 4ull                         // key0
                + (size_t)RB * NB * 4ull                    // hist
                + (size_t)RB * 4ull                         // dtot
                + (size_t)NP8 * 8ull                        // flags8
                + (size_t)NP8 * 4ull                        // wpfx
                + (size_t)NWB * 4ull + 64ull;               // wsum + pad
    if (ws_size < need) return;
    if ((size_t)out_size < (size_t)VN_OFF + 1) return;

    u64* pairA  = (u64*)d_ws;
    int* key0   = (int*)(pairA + NP);
    int* hist   = key0 + NP;
    int* dtot   = hist + (size_t)RB * NB;
    u64* flags8 = (u64*)(dtot + RB);              // 8B-aligned (offset even #ints)
    int* wpfx   = (int*)(flags8 + NP8);
    int* wsum   = wpfx + NP8;
    float* out  = (float*)d_out;

    vx_prep<<<NB, BLK, 0, stream>>>(pts, vsz, crg, key0, hist, flags8, out, NP, NP8);
    vx_scanw<<<RB / 4, BLK, 0, stream>>>(hist, dtot, NB);
    vx_scat<<<NB, BLK, 0, stream>>>(key0, hist, dtot, pairA, NP);
    vx_bsort<<<RB, 512, 0, stream>>>(pairA, dtot, flags8);
    vx_wpA<<<NWB, BLK, 0, stream>>>(flags8, wsum, NP8);
    vx_wp2<<<NWB, BLK, 0, stream>>>(flags8, wsum, wpfx, out + VN_OFF, NP8);
    vx_emit<<<RB, BLK, 0, stream>>>(pairA, dtot, flags8, wpfx, pts, vsz, crg, out);
}